// Round 10
// baseline (147.562 us; speedup 1.0000x reference)
//
#include <hip/hip_runtime.h>

// GCN link-prediction forward: 2× GCNConv (128->128 relu, 128->64) on
// N=50000 nodes, E=800000 random edges. fp32 compute, int8 messages.
//
// Algebra: with dis[n] = rsqrt(indeg[n]+1),
//   conv(x)[c] = ( sum_{r->c} h[r]*dis[r] + h[c]*dis[c] ) * dis[c] + b,
//   h = x@W (unscaled). Messages stored int8 (per-row scale, biased +128;
//   exact -128 correction via K = sum of scales).
//
// R2..R9: 2737 -> 169 us. R10: src-sort falsified. R11: int8 L1 msgs: 161.
// R12/R14: int8 L2 msgs; gathers LATENCY-bound. R15: W pre-pack: 158.8.
// R16: de-shuffled gathers (16B ushort8 idx loads): 152.1.
// R17: cooperative fusion: 301 (grid.sync ~100us+/sync on 8 XCDs; front
//      phases nearly idle: VALU 1%, HBM 2% -> front is STALL, not work).
// R18: dummy-pad+unroll: +4. R19: fixed sub-windows: +15 (slot overhead).
// R20: in-block W1 conversion: +9.7 (782x redundant). All REVERTED.
// R21: k_csr 1024thr + LDS edge cache: 149.4. Targeted fixes win.
// R22: NPB 256 (196 csr blocks, 77% CU coverage): 146.2. BEST.
// R23: partition blocks LDS-sort their 4096 edges by bucket, write ONE
//      coalesced 16KB chunk + inclusive prefix table inclg[chunk][bkt];
//      k_csr rebuilds buckets from 196 variable runs (4 thr/chunk copy,
//      work proportional to edges -- R19's div/mod slot poison avoided).
//      Kills 800K scattered 4B stores + cross-XCD partial-line writeback
//      + global cursor atomics + memset. Downstream byte-identical.

typedef unsigned int u32;
typedef unsigned short ushort;
typedef __attribute__((ext_vector_type(8))) short short8;
typedef __attribute__((ext_vector_type(8))) unsigned short us8;
typedef __attribute__((ext_vector_type(4))) float floatx4;

static inline int cdiv_l(long a, int b) { return (int)((a + b - 1) / b); }

constexpr int NPB  = 256;    // nodes per bucket (2^8)
constexpr int EPB  = 4096;   // edges per partition block/chunk
constexpr int MAXB = 256;    // max buckets (N <= 65536)
constexpr int CAP  = 8192;   // per-bucket csr window / csr LDS cache
// bucket mean 4082, sigma ~64 -> 8192 is +64 sigma; padded worst ~5874.

__device__ __forceinline__ u32 pack_bf16(float a, float b) {
  union { float f; u32 i; } ua, ub;
  ua.f = a; ub.f = b;
  u32 x = (ua.i + 0x7fffu + ((ua.i >> 16) & 1u)) >> 16;           // rne, low
  u32 y = (ub.i + 0x7fffu + ((ub.i >> 16) & 1u)) & 0xffff0000u;   // rne, high
  return x | y;
}

__device__ __forceinline__ short bf16r(float f) {
  union { float f; u32 i; } u; u.f = f;
  return (short)((u.i + 0x7fffu + ((u.i >> 16) & 1u)) >> 16);     // rne
}

// int8 dequant-accumulate: 8 biased uint8 -> acc += (float)q * sd
// (the -128 bias is corrected once per node via K = sum of sd).
__device__ __forceinline__ void dq8(float* a, uint2 v, float sd) {
  a[0] += (float)(v.x & 255u) * sd;
  a[1] += (float)((v.x >> 8) & 255u) * sd;
  a[2] += (float)((v.x >> 16) & 255u) * sd;
  a[3] += (float)(v.x >> 24) * sd;
  a[4] += (float)(v.y & 255u) * sd;
  a[5] += (float)((v.y >> 8) & 255u) * sd;
  a[6] += (float)((v.y >> 16) & 255u) * sd;
  a[7] += (float)(v.y >> 24) * sd;
}

// ---- dispatch 0: pack W1/W2 into MFMA B-fragment bf16 ----
// Fragment layout: slot s = frag*64 + lane; frag = kc*(M/16) + cb.
// Lane's short8: elem j = bf16(W[(kc*32 + (lane>>4)*8 + j)*M + cb*16 + (lane&15)])
// so GEMM B-load is ONE coalesced 16B read, zero conversion VALU.
__global__ __launch_bounds__(256) void k_pack(
    const float* __restrict__ W1, const float* __restrict__ W2,
    u32* __restrict__ w1f, u32* __restrict__ w2f) {
  const int tid = threadIdx.x;
  const int b = blockIdx.x;
  if (b < 8) {
    // W1: 128x128 -> 2048 slots (8 blocks x 256)
    const int s = b * 256 + tid;
    const int lane = s & 63, frag = s >> 6;
    const int kc = frag >> 3, cb = frag & 7;
    const float* src =
        W1 + (long)(kc * 32 + (lane >> 4) * 8) * 128 + cb * 16 + (lane & 15);
    u32 o[4];
#pragma unroll
    for (int p = 0; p < 4; ++p)
      o[p] = pack_bf16(src[(2 * p) * 128], src[(2 * p + 1) * 128]);
    *(uint4*)(w1f + (long)s * 4) = make_uint4(o[0], o[1], o[2], o[3]);
  } else {
    // W2: 128x64 -> 1024 slots (4 blocks x 256)
    const int s = (b - 8) * 256 + tid;
    const int lane = s & 63, frag = s >> 6;
    const int kc = frag >> 2, cb = frag & 3;
    const float* src =
        W2 + (long)(kc * 32 + (lane >> 4) * 8) * 64 + cb * 16 + (lane & 15);
    u32 o[4];
#pragma unroll
    for (int p = 0; p < 4; ++p)
      o[p] = pack_bf16(src[(2 * p) * 64], src[(2 * p + 1) * 64]);
    *(uint4*)(w2f + (long)s * 4) = make_uint4(o[0], o[1], o[2], o[3]);
  }
}

// ---- fused dispatch 1: blocks [0,NBE): bucket-sort 4096 edges in LDS,
// ---- write coalesced chunk + inclusive prefix; [NBE,..): MFMA GEMM1.
__global__ __launch_bounds__(256) void k_fused1(
    const int* __restrict__ ei, u32* __restrict__ ebuf,
    int* __restrict__ inclg, int E, int NBE,
    const float* __restrict__ x, const u32* __restrict__ w1f,
    u32* __restrict__ h8, float* __restrict__ scale, int N) {
  __shared__ __align__(16) char smem[35072];   // union workspace
  const int tid = threadIdx.x;

  if (blockIdx.x < (unsigned)NBE) {
    // ===== edge partition: LDS counting sort, coalesced chunk out =====
    u32* ecache = (u32*)smem;              // 4096 u32 = 16 KB
    u32* sorted = ecache + EPB;            // 4096 u32 = 16 KB
    int* hist   = (int*)(sorted + EPB);    // 256
    int* pexcl  = hist + MAXB;             // 256 (excl prefix -> cursor)
    int* wsum4  = pexcl + MAXB;            // 4
    const int* ecol = ei + E;
    hist[tid] = 0;
    __syncthreads();
    const int base = blockIdx.x * EPB;
#pragma unroll
    for (int j = 0; j < EPB / 256; ++j) {
      int e = base + j * 256 + tid;
      u32 pk = 0xffffffffu;
      if (e < E) {
        u32 r = (u32)ei[e];
        u32 c = (u32)ecol[e];
        pk = r | (c << 16);
        atomicAdd(hist + (c >> 8), 1);
      }
      ecache[j * 256 + tid] = pk;
    }
    __syncthreads();
    // 256-entry exclusive prefix (4 waves)
    const int lane = tid & 63, w = tid >> 6;
    const int v = hist[tid];
    int incl = v;
#pragma unroll
    for (int d = 1; d < 64; d <<= 1) {
      int xx = __shfl_up(incl, d, 64);
      if (lane >= d) incl += xx;
    }
    if (lane == 63) wsum4[w] = incl;
    __syncthreads();
    if (w == 0 && lane < 4) {
      int sv = wsum4[lane];
#pragma unroll
      for (int d = 1; d < 4; d <<= 1) {
        int xx = __shfl_up(sv, d, 64);
        if (lane >= d) sv += xx;
      }
      wsum4[lane] = sv;
    }
    __syncthreads();
    const int excl = ((w > 0) ? wsum4[w - 1] : 0) + incl - v;
    inclg[blockIdx.x * MAXB + tid] = excl + v;   // inclusive prefix (global)
    pexcl[tid] = excl;                           // local cursor
    __syncthreads();
    // local scatter into sorted[]
#pragma unroll
    for (int j = 0; j < EPB / 256; ++j) {
      u32 pk = ecache[j * 256 + tid];
      if (pk != 0xffffffffu) {
        u32 c16 = pk >> 16;
        int p = atomicAdd(pexcl + (c16 >> 8), 1);
        sorted[p] = (pk & 0xffffu) | ((c16 & 255u) << 16);
      }
    }
    __syncthreads();
    // coalesced chunk write-out
    const int tot = pexcl[MAXB - 1];   // == total valid edges in chunk
    u32* gout = ebuf + (long)blockIdx.x * EPB;
    for (int i = tid; i < tot; i += 256) gout[i] = sorted[i];
    return;
  }

  // ===== MFMA GEMM1: h8[row,:] = int8(x[row,:] @ W1), K=M=128 =====
  constexpr int K = 128, NC = 8, LROW = 133;
  const int w = tid >> 6, lane = tid & 63;
  const int quad = lane >> 4, n16 = lane & 15;
  const int row0 = ((blockIdx.x - NBE) * 4 + w) * 16;

  floatx4 acc[NC];
#pragma unroll
  for (int c = 0; c < NC; ++c) acc[c] = {0.f, 0.f, 0.f, 0.f};

  const int am = row0 + n16;
  const bool av = am < N;
  const float* arow = x + (long)am * K;
  const short8* wf = (const short8*)w1f;

#pragma unroll
  for (int kc = 0; kc < 4; ++kc) {
    const int kb = kc * 32 + quad * 8;
    float4 a0 = make_float4(0.f, 0.f, 0.f, 0.f);
    float4 a1 = make_float4(0.f, 0.f, 0.f, 0.f);
    if (av) {
      a0 = *(const float4*)(arow + kb);
      a1 = *(const float4*)(arow + kb + 4);
    }
    short8 af;
    af[0] = bf16r(a0.x); af[1] = bf16r(a0.y); af[2] = bf16r(a0.z); af[3] = bf16r(a0.w);
    af[4] = bf16r(a1.x); af[5] = bf16r(a1.y); af[6] = bf16r(a1.z); af[7] = bf16r(a1.w);
#pragma unroll
    for (int c = 0; c < NC; ++c) {
      short8 bf = wf[(kc * 8 + c) * 64 + lane];
      acc[c] = __builtin_amdgcn_mfma_f32_16x16x32_bf16(af, bf, acc[c], 0, 0, 0);
    }
  }

  float* ep = (float*)smem + w * (16 * LROW);
#pragma unroll
  for (int c = 0; c < NC; ++c)
#pragma unroll
    for (int r = 0; r < 4; ++r)
      ep[(quad * 4 + r) * LROW + c * 16 + n16] = acc[c][r];
  __syncthreads();

  // int8 quantize: lane -> row rr = lane>>2, col segment seg*32..+31
  const int rr = lane >> 2, seg = lane & 3;
  const float* rowp = ep + rr * LROW + seg * 32;
  float m = 0.f;
#pragma unroll
  for (int c = 0; c < 32; ++c) m = fmaxf(m, fabsf(rowp[c]));
  m = fmaxf(m, __shfl_xor(m, 1, 4));
  m = fmaxf(m, __shfl_xor(m, 2, 4));
  const float inv = (m > 0.f) ? 127.f / m : 0.f;
  const float s = m / 127.f;
  u32 q[8];
#pragma unroll
  for (int wd = 0; wd < 8; ++wd) {
    u32 b0 = (u32)((int)rintf(rowp[wd * 4 + 0] * inv) + 128);
    u32 b1 = (u32)((int)rintf(rowp[wd * 4 + 1] * inv) + 128);
    u32 b2 = (u32)((int)rintf(rowp[wd * 4 + 2] * inv) + 128);
    u32 b3 = (u32)((int)rintf(rowp[wd * 4 + 3] * inv) + 128);
    q[wd] = (b0 & 255u) | ((b1 & 255u) << 8) | ((b2 & 255u) << 16) | (b3 << 24);
  }
  const int rg = row0 + rr;
  if (rg < N) {
    uint4* dst = (uint4*)(h8 + (long)rg * 32 + seg * 8);
    dst[0] = make_uint4(q[0], q[1], q[2], q[3]);
    dst[1] = make_uint4(q[4], q[5], q[6], q[7]);
    if (seg == 0) scale[rg] = s;
  }
}

// ---- dispatch 2: per-bucket CSR finalize from sorted chunks + sd fold;
// ---- node list starts padded to 8 (aligned us8 index loads). ----
__global__ __launch_bounds__(1024) void k_csr(const u32* __restrict__ ebuf,
                                              const int* __restrict__ inclg,
                                              const float* __restrict__ scale,
                                              int* __restrict__ off,
                                              int* __restrict__ deg,
                                              float* __restrict__ dis,
                                              float* __restrict__ sd,
                                              ushort* __restrict__ csr,
                                              int NBE, int N) {
  __shared__ u32 ecache[CAP];     // 32 KB bucket edge cache
  __shared__ int rs[256], rl[256], gp[256];
  __shared__ int cnt[NPB];
  __shared__ int curl[NPB];
  __shared__ int wsum[4];
  __shared__ int tot_s;
  const int tid = threadIdx.x;
  const int b = blockIdx.x;
  const int lane = tid & 63, w = tid >> 6;

  // run table: chunk c contributes [rs[c], rs[c]+rl[c]) of its chunk
  if (tid < 256) {
    if (tid < NBE) {
      int inc = inclg[tid * MAXB + b];
      int prev = (b > 0) ? inclg[tid * MAXB + b - 1] : 0;
      rs[tid] = prev;
      rl[tid] = inc - prev;
    } else {
      rs[tid] = 0; rl[tid] = 0;
    }
    cnt[tid] = 0;
  }
  __syncthreads();
  // scan A: run lengths -> gp (exclusive), tot
  if (tid < 256) {
    const int rv = rl[tid];
    int rincl = rv;
#pragma unroll
    for (int d = 1; d < 64; d <<= 1) {
      int xx = __shfl_up(rincl, d, 64);
      if (lane >= d) rincl += xx;
    }
    if (lane == 63) wsum[w] = rincl;
  }
  __syncthreads();
  if (w == 0 && lane < 4) {
    int sv = wsum[lane];
#pragma unroll
    for (int d = 1; d < 4; d <<= 1) {
      int xx = __shfl_up(sv, d, 64);
      if (lane >= d) sv += xx;
    }
    wsum[lane] = sv;
  }
  __syncthreads();
  if (tid < 256) {
    const int rv = rl[tid];
    int rincl = rv;
#pragma unroll
    for (int d = 1; d < 64; d <<= 1) {
      int xx = __shfl_up(rincl, d, 64);
      if (lane >= d) rincl += xx;
    }
    gp[tid] = ((w > 0) ? wsum[w - 1] : 0) + rincl - rv;
    if (tid == 255) tot_s = gp[255] + rv;
  }
  __syncthreads();
  const int tot = min(tot_s, CAP);
  // copy runs into ecache: 4 threads per chunk
  {
    const int c4 = tid;
    if (c4 < NBE * 4) {
      const int c = c4 >> 2, j = c4 & 3;
      const long src = (long)c * EPB + rs[c];
      const int len = rl[c], g0 = gp[c];
      for (int k = j; k < len; k += 4)
        if (g0 + k < CAP) ecache[g0 + k] = ebuf[src + k];
    }
  }
  __syncthreads();
  // count pass
  for (int i = tid; i < tot; i += 1024)
    atomicAdd(cnt + (ecache[i] >> 16), 1);
  __syncthreads();
  // scan B: padded node-degree prefix (8-aligned starts)
  int v = 0, vp = 0, incl = 0;
  if (tid < NPB) {
    v = cnt[tid];
    vp = (v + 7) & ~7;
    incl = vp;
#pragma unroll
    for (int d = 1; d < 64; d <<= 1) {
      int xx = __shfl_up(incl, d, 64);
      if (lane >= d) incl += xx;
    }
    if (lane == 63) wsum[w] = incl;
  }
  __syncthreads();
  if (w == 0 && lane < NPB / 64) {
    int sv = wsum[lane];
#pragma unroll
    for (int d = 1; d < NPB / 64; d <<= 1) {
      int xx = __shfl_up(sv, d, 64);
      if (lane >= d) sv += xx;
    }
    wsum[lane] = sv;
  }
  __syncthreads();
  if (tid < NPB) {
    const int excl = ((w > 0) ? wsum[w - 1] : 0) + incl - vp;
    const int node = b * NPB + tid;
    if (node < N) {
      float dv = rsqrtf((float)v + 1.0f);
      off[node] = b * CAP + excl;
      deg[node] = v;
      dis[node] = dv;
      sd[node] = scale[node] * dv;
    }
    curl[tid] = excl;
  }
  __syncthreads();
  // scatter
  ushort* cw = csr + (long)b * CAP;
  for (int i = tid; i < tot; i += 1024) {
    u32 pk = ecache[i];
    int p = atomicAdd(curl + (pk >> 16), 1);
    cw[p] = (ushort)(pk & 0xffffu);
  }
}

// ---- dispatch 3: fused gather1 (int8 msgs, direct idx loads) + relu +
// ---- GEMM2; epilogue quantizes h2 to int8 (per-row scale s2). ----
__global__ __launch_bounds__(256) void k_gg(
    const uint2* __restrict__ h8, const int* __restrict__ off,
    const int* __restrict__ deg, const ushort* __restrict__ csr,
    const float* __restrict__ dis, const float* __restrict__ sd,
    const float* __restrict__ b1, const u32* __restrict__ w2f,
    u32* __restrict__ h2, float* __restrict__ s2, int N) {
  constexpr int LG = 65;   // u32 words per g row (64 + pad)
  constexpr int LC = 66;   // f32 words per C row (64 + pad)
  __shared__ u32 lg[16 * LG];
  __shared__ float cb[16 * LC];
  const int tid = threadIdx.x;
  const int r = tid >> 4;          // local node 0..15
  const int lf = tid & 15;         // lane within 16-group (8-byte chunk)
  const int row0 = blockIdx.x * 16;
  const int n = row0 + r;

  // ---- phase 1: int8 gather (rows = 128B = 2 lines) ----
  u32 gw[4] = {0, 0, 0, 0};
  if (n < N) {
    const int s = off[n], e = s + deg[n];
    const float dn = dis[n];
    float acc[8] = {};
    float K = 0.f;
    {
      float sn = sd[n];
      dq8(acc, h8[(long)n * 16 + lf], sn);  // self-loop
      K += sn;
    }
    int j = s;
    for (; j + 8 <= e; j += 8) {
      us8 ev = *(const us8*)(csr + j);   // 16B aligned broadcast load
      const int i0 = ev[0], i1 = ev[1], i2 = ev[2], i3 = ev[3];
      const int i4 = ev[4], i5 = ev[5], i6 = ev[6], i7 = ev[7];
      const float d0 = sd[i0], d1 = sd[i1], d2 = sd[i2], d3 = sd[i3];
      const float d4 = sd[i4], d5 = sd[i5], d6 = sd[i6], d7 = sd[i7];
      uint2 v0 = h8[(long)i0 * 16 + lf];
      uint2 v1 = h8[(long)i1 * 16 + lf];
      uint2 v2 = h8[(long)i2 * 16 + lf];
      uint2 v3 = h8[(long)i3 * 16 + lf];
      uint2 v4 = h8[(long)i4 * 16 + lf];
      uint2 v5 = h8[(long)i5 * 16 + lf];
      uint2 v6 = h8[(long)i6 * 16 + lf];
      uint2 v7 = h8[(long)i7 * 16 + lf];
      dq8(acc, v0, d0); dq8(acc, v1, d1); dq8(acc, v2, d2); dq8(acc, v3, d3);
      dq8(acc, v4, d4); dq8(acc, v5, d5); dq8(acc, v6, d6); dq8(acc, v7, d7);
      K += ((d0 + d1) + (d2 + d3)) + ((d4 + d5) + (d6 + d7));
    }
    if (j < e) {
      us8 ev = *(const us8*)(csr + j);
#pragma unroll
      for (int t = 0; t < 8; ++t) {
        if (j + t < e) {
          const int it = ev[t];
          const float dt = sd[it];
          dq8(acc, h8[(long)it * 16 + lf], dt);
          K += dt;
        }
      }
    }
    const int f8 = lf * 8;
    const float4 bv0 = *(const float4*)(b1 + f8);
    const float4 bv1 = *(const float4*)(b1 + f8 + 4);
    const float bb[8] = {bv0.x, bv0.y, bv0.z, bv0.w, bv1.x, bv1.y, bv1.z, bv1.w};
    const float kc = 128.f * K;
#pragma unroll
    for (int q = 0; q < 8; ++q)
      acc[q] = fmaxf((acc[q] - kc) * dn + bb[q], 0.f);
#pragma unroll
    for (int q = 0; q < 4; ++q)
      gw[q] = pack_bf16(acc[2 * q], acc[2 * q + 1]);
  }
#pragma unroll
  for (int q = 0; q < 4; ++q) lg[r * LG + lf * 4 + q] = gw[q];
  __syncthreads();

  // ---- phase 2: 16x128x64 MFMA; wave w owns cols w*16..w*16+15 ----
  const int w = tid >> 6, lane = tid & 63;
  const int quad = lane >> 4, n16 = lane & 15;
  floatx4 acc4 = {0.f, 0.f, 0.f, 0.f};
#pragma unroll
  for (int kc = 0; kc < 4; ++kc) {
    const int kb = kc * 32 + quad * 8;
    const u32* ap = &lg[n16 * LG + (kb >> 1)];
    u32 aw[4] = {ap[0], ap[1], ap[2], ap[3]};
    short8 af = *(short8*)aw;
    short8 bf = ((const short8*)w2f)[(kc * 4 + w) * 64 + lane];
    acc4 = __builtin_amdgcn_mfma_f32_16x16x32_bf16(af, bf, acc4, 0, 0, 0);
  }
  float dd[4];
#pragma unroll
  for (int r4 = 0; r4 < 4; ++r4) {
    int rg = row0 + quad * 4 + r4;
    dd[r4] = (rg < N) ? dis[rg] : 0.f;
  }
#pragma unroll
  for (int r4 = 0; r4 < 4; ++r4)
    cb[(quad * 4 + r4) * LC + w * 16 + n16] = acc4[r4] * dd[r4];
  __syncthreads();

  // ---- int8 quantize h2 rows: 16 lanes per row, 4 cols each ----
  const int rr2 = tid >> 4, lf2 = tid & 15;
  const float* rp = cb + rr2 * LC + lf2 * 4;
  float mx = fmaxf(fmaxf(fabsf(rp[0]), fabsf(rp[1])),
                   fmaxf(fabsf(rp[2]), fabsf(rp[3])));
  mx = fmaxf(mx, __shfl_xor(mx, 1, 16));
  mx = fmaxf(mx, __shfl_xor(mx, 2, 16));
  mx = fmaxf(mx, __shfl_xor(mx, 4, 16));
  mx = fmaxf(mx, __shfl_xor(mx, 8, 16));
  const float inv2 = (mx > 0.f) ? 127.f / mx : 0.f;
  const int rg2 = row0 + rr2;
  if (rg2 < N) {
    u32 q0 = (u32)((int)rintf(rp[0] * inv2) + 128);
    u32 q1 = (u32)((int)rintf(rp[1] * inv2) + 128);
    u32 q2 = (u32)((int)rintf(rp[2] * inv2) + 128);
    u32 q3 = (u32)((int)rintf(rp[3] * inv2) + 128);
    h2[(long)rg2 * 16 + lf2] =
        (q0 & 255u) | ((q1 & 255u) << 8) | ((q2 & 255u) << 16) | (q3 << 24);
    if (lf2 == 0) s2[rg2] = mx / 127.f;
  }
}

// ---- dispatch 4: layer-2 gather (int8 h2, direct idx loads) + bias ----
__global__ __launch_bounds__(256) void k_gather2(
    const uint2* __restrict__ hs, const int* __restrict__ off,
    const int* __restrict__ deg, const ushort* __restrict__ csr,
    const float* __restrict__ dis, const float* __restrict__ sc2,
    const float* __restrict__ bias, float* __restrict__ out, int N) {
  constexpr int L = 8;  // lanes per node
  const int local = threadIdx.x / L;
  const int lf = threadIdx.x % L;
  const int n = blockIdx.x * (256 / L) + local;
  if (n >= N) return;
  const int s = off[n], e = s + deg[n];
  float acc[8] = {};
  float K = 0.f;
  {
    float t0 = sc2[n];
    dq8(acc, hs[(long)n * L + lf], t0);  // self-loop
    K += t0;
  }
  int j = s;
  for (; j + 8 <= e; j += 8) {
    us8 ev = *(const us8*)(csr + j);   // 16B aligned broadcast load
    const int i0 = ev[0], i1 = ev[1], i2 = ev[2], i3 = ev[3];
    const int i4 = ev[4], i5 = ev[5], i6 = ev[6], i7 = ev[7];
    const float d0 = sc2[i0], d1 = sc2[i1], d2 = sc2[i2], d3 = sc2[i3];
    const float d4 = sc2[i4], d5 = sc2[i5], d6 = sc2[i6], d7 = sc2[i7];
    uint2 v0 = hs[(long)i0 * L + lf];
    uint2 v1 = hs[(long)i1 * L + lf];
    uint2 v2 = hs[(long)i2 * L + lf];
    uint2 v3 = hs[(long)i3 * L + lf];
    uint2 v4 = hs[(long)i4 * L + lf];
    uint2 v5 = hs[(long)i5 * L + lf];
    uint2 v6 = hs[(long)i6 * L + lf];
    uint2 v7 = hs[(long)i7 * L + lf];
    dq8(acc, v0, d0); dq8(acc, v1, d1); dq8(acc, v2, d2); dq8(acc, v3, d3);
    dq8(acc, v4, d4); dq8(acc, v5, d5); dq8(acc, v6, d6); dq8(acc, v7, d7);
    K += ((d0 + d1) + (d2 + d3)) + ((d4 + d5) + (d6 + d7));
  }
  if (j < e) {
    us8 ev = *(const us8*)(csr + j);
#pragma unroll
    for (int t = 0; t < 8; ++t) {
      if (j + t < e) {
        const int it = ev[t];
        const float dt = sc2[it];
        dq8(acc, hs[(long)it * L + lf], dt);
        K += dt;
      }
    }
  }
  const float d = dis[n];
  const float kc = 128.f * K;
  const int f8 = lf * 8;
  const float4 b0 = *(const float4*)(bias + f8);
  const float4 b1v = *(const float4*)(bias + f8 + 4);
  float4 o0, o1;
  o0.x = (acc[0] - kc) * d + b0.x;
  o0.y = (acc[1] - kc) * d + b0.y;
  o0.z = (acc[2] - kc) * d + b0.z;
  o0.w = (acc[3] - kc) * d + b0.w;
  o1.x = (acc[4] - kc) * d + b1v.x;
  o1.y = (acc[5] - kc) * d + b1v.y;
  o1.z = (acc[6] - kc) * d + b1v.z;
  o1.w = (acc[7] - kc) * d + b1v.w;
  *(float4*)(out + (long)n * 64 + f8) = o0;
  *(float4*)(out + (long)n * 64 + f8 + 4) = o1;
}

extern "C" void kernel_launch(void* const* d_in, const int* in_sizes, int n_in,
                              void* d_out, int out_size, void* d_ws, size_t ws_size,
                              hipStream_t stream) {
  const float* x  = (const float*)d_in[0];
  const int*   ei = (const int*)d_in[1];   // [2,E] int32
  const float* W1 = (const float*)d_in[4];
  const float* b1 = (const float*)d_in[5];
  const float* W2 = (const float*)d_in[6];
  const float* b2 = (const float*)d_in[7];
  float* out = (float*)d_out;

  const int N = in_sizes[0] / 128;
  const int E = in_sizes[1] / 2;
  const int NBKT = cdiv_l(N, NPB);   // 196 (<=256; N<=65536 for 16-bit pack)
  const int NBE  = cdiv_l(E, EPB);   // 196 chunks (<=256 for run tables)
  const int G1   = cdiv_l(N, 64);    // 782 gemm1 blocks

  // workspace layout (4-byte elems):
  //   inclg[NBE*MAXB] | off[Np] | deg[Np] | dis[Np] | scale[Np] | sd[Np]
  //   | s2[Np] | w1f[8192] | w2f[4096] | ebuf[NBE*EPB u32]
  //   | csr[NBKT*CAP ushort] | h8[N*32 u32] | h2[N*16 u32]
  const long Np = (N + 64) & ~63L;
  int*    inclg = (int*)d_ws;
  int*    off   = inclg + (long)NBE * MAXB;
  int*    deg   = off + Np;
  float*  dis   = (float*)(deg + Np);
  float*  scale = dis + Np;
  float*  sd    = scale + Np;
  float*  s2    = sd + Np;
  u32*    w1f   = (u32*)(s2 + Np);       // 2048 slots * 4 u32 = 32 KB
  u32*    w2f   = w1f + 8192;            // 1024 slots * 4 u32 = 16 KB
  u32*    ebuf  = w2f + 4096;
  ushort* csr   = (ushort*)(ebuf + (long)NBE * EPB);
  u32*    h8    = (u32*)(csr + (long)NBKT * CAP);
  u32*    h2    = h8 + (long)N * 32;

  // ---- W1/W2 fragment-pack (no cursors needed anymore) ----
  k_pack<<<12, 256, 0, stream>>>(W1, W2, w1f, w2f);

  // ---- fused: edge partition (sorted chunks) || GEMM1+int8 ----
  k_fused1<<<NBE + G1, 256, 0, stream>>>(ei, ebuf, inclg, E, NBE, x, w1f, h8,
                                         scale, N);

  // ---- per-bucket CSR finalize from runs (+ sd fold, 8-aligned starts) ----
  k_csr<<<NBKT, 1024, 0, stream>>>(ebuf, inclg, scale, off, deg, dis, sd, csr,
                                   NBE, N);

  // ---- gather1 (int8) + relu + GEMM2 fused + h2 int8 quantize ----
  k_gg<<<cdiv_l(N, 16), 256, 0, stream>>>((const uint2*)h8, off, deg, csr,
                                          dis, sd, b1, w2f, h2, s2, N);

  // ---- layer-2 gather (int8) + bias ----
  k_gather2<<<cdiv_l(N, 32), 256, 0, stream>>>((const uint2*)h2, off, deg, csr,
                                               dis, s2, b2, out, N);
}